// Round 4
// baseline (145.047 us; speedup 1.0000x reference)
//
#include <hip/hip_runtime.h>

// Problem constants (from reference): B=128, L=1024, D=2048, f32 in/out.
constexpr int Bc = 128;
constexpr int Lc = 1024;
constexpr int Dc = 2048;

constexpr int THREADS   = 256;
constexpr int VEC       = 4;                   // float4 per thread
constexpr int DCOLS_BLK = THREADS * VEC;       // 1024 columns per block
constexpr int DBLKS     = Dc / DCOLS_BLK;      // 2
constexpr int NL        = 32;                  // row-interleave groups (4x oversubscription
                                               // vs full residency -> dynamic load balance)

typedef float v4f __attribute__((ext_vector_type(4)));

__global__ __launch_bounds__(THREADS) void avg_pool_var_kernel(
    const float* __restrict__ feat,
    const int*   __restrict__ lengths,
    float*       __restrict__ out)
{
    // blockIdx.x encodes (b, dblk, lc); lc picks rows l ≡ lc (mod NL)
    int bid  = blockIdx.x;
    int lc   = bid % NL;
    int dblk = (bid / NL) % DBLKS;
    int b    = bid / (NL * DBLKS);

    int len = lengths[b];
    int eff = (len > 0) ? len : Lc;
    if (lc >= eff) return;                     // block-uniform early-out

    int col = dblk * DCOLS_BLK + (int)threadIdx.x * VEC;
    const float* p = feat + (size_t)b * Lc * Dc + (size_t)lc * Dc + col;

    float ax = 0.f, ay = 0.f, az = 0.f, aw = 0.f;
    #pragma unroll 4
    for (int l = lc; l < eff; l += NL, p += (size_t)NL * Dc) {
        v4f v = __builtin_nontemporal_load(reinterpret_cast<const v4f*>(p));
        ax += v.x; ay += v.y; az += v.z; aw += v.w;
    }

    float inv = 1.0f / (float)eff;
    float* o = out + (size_t)b * Dc + col;
    atomicAdd(o + 0, ax * inv);
    atomicAdd(o + 1, ay * inv);
    atomicAdd(o + 2, az * inv);
    atomicAdd(o + 3, aw * inv);
}

extern "C" void kernel_launch(void* const* d_in, const int* in_sizes, int n_in,
                              void* d_out, int out_size, void* d_ws, size_t ws_size,
                              hipStream_t stream)
{
    const float* feat    = (const float*)d_in[0];
    const int*   lengths = (const int*)d_in[1];
    float*       out     = (float*)d_out;

    // Harness poisons d_out once and never re-poisons between replays:
    // zero it every call (graph-capture-safe memset node).
    (void)hipMemsetAsync(out, 0, (size_t)out_size * sizeof(float), stream);

    dim3 grid(Bc * DBLKS * NL);
    dim3 block(THREADS);
    avg_pool_var_kernel<<<grid, block, 0, stream>>>(feat, lengths, out);
}

// Round 5
// 108.109 us; speedup vs baseline: 1.3417x; 1.3417x over previous
//
#include <hip/hip_runtime.h>

// Problem constants (from reference): B=128, L=1024, D=2048, f32 in/out.
constexpr int Bc = 128;
constexpr int Lc = 1024;
constexpr int Dc = 2048;

constexpr int THREADS = 512;                 // 512 x float4 = one full 2048-col row / iter
constexpr int GRID    = 1024;                // 4 blocks/CU x 256 CU = exactly full residency

typedef float v4f __attribute__((ext_vector_type(4)));

__global__ __launch_bounds__(THREADS) void avg_pool_var_kernel(
    const float* __restrict__ feat,
    const int*   __restrict__ lengths,
    float*       __restrict__ out)
{
    __shared__ int E[Bc];        // eff per batch
    __shared__ int S[Bc + 1];    // exclusive prefix of eff

    int tid = threadIdx.x;
    if (tid < Bc) {
        int len = lengths[tid];
        E[tid] = (len > 0) ? len : Lc;
    }
    __syncthreads();
    if (tid == 0) {
        int s = 0;
        #pragma unroll 8
        for (int b = 0; b < Bc; ++b) { S[b] = s; s += E[b]; }
        S[Bc] = s;
    }
    __syncthreads();

    int total = S[Bc];
    // Equal contiguous slice of the flattened row list for this block.
    int r0 = (int)((long long)blockIdx.x * total / GRID);
    int r1 = (int)((long long)(blockIdx.x + 1) * total / GRID);
    if (r0 >= r1) return;

    // Binary search: largest b with S[b] <= r0.  (Uniform across the block.)
    int lo = 0, hi = Bc - 1;
    while (lo < hi) {
        int mid = (lo + hi + 1) >> 1;
        if (S[mid] <= r0) lo = mid; else hi = mid - 1;
    }
    int cur_b = lo;
    int nb    = S[cur_b + 1];    // next batch boundary (register)

    int col = tid * 4;
    float ax = 0.f, ay = 0.f, az = 0.f, aw = 0.f;

    for (int r = r0; r < r1; ++r) {
        if (r >= nb) {
            // flush partial sum for cur_b
            float inv = 1.0f / (float)(nb - S[cur_b]);
            float* o = out + (size_t)cur_b * Dc + col;
            atomicAdd(o + 0, ax * inv);
            atomicAdd(o + 1, ay * inv);
            atomicAdd(o + 2, az * inv);
            atomicAdd(o + 3, aw * inv);
            ax = ay = az = aw = 0.f;
            while (r >= S[cur_b + 1]) ++cur_b;   // eff >= 1, but stay safe
            nb = S[cur_b + 1];
        }
        int l = r - S[cur_b];
        const float* p = feat + ((size_t)cur_b * Lc + l) * Dc + col;
        v4f v = __builtin_nontemporal_load(reinterpret_cast<const v4f*>(p));
        ax += v.x; ay += v.y; az += v.z; aw += v.w;
    }
    // final flush
    {
        float inv = 1.0f / (float)(nb - S[cur_b]);
        float* o = out + (size_t)cur_b * Dc + col;
        atomicAdd(o + 0, ax * inv);
        atomicAdd(o + 1, ay * inv);
        atomicAdd(o + 2, az * inv);
        atomicAdd(o + 3, aw * inv);
    }
}

extern "C" void kernel_launch(void* const* d_in, const int* in_sizes, int n_in,
                              void* d_out, int out_size, void* d_ws, size_t ws_size,
                              hipStream_t stream)
{
    const float* feat    = (const float*)d_in[0];
    const int*   lengths = (const int*)d_in[1];
    float*       out     = (float*)d_out;

    // Harness poisons d_out once and never re-poisons between replays:
    // zero it every call (graph-capture-safe memset node).
    (void)hipMemsetAsync(out, 0, (size_t)out_size * sizeof(float), stream);

    avg_pool_var_kernel<<<dim3(GRID), dim3(THREADS), 0, stream>>>(feat, lengths, out);
}